// Round 3
// baseline (1150.046 us; speedup 1.0000x reference)
//
#include <hip/hip_runtime.h>
#include <hip/hip_bf16.h>

#define DD 4096
#define NTOK 8192

using u16 = unsigned short;

typedef __attribute__((ext_vector_type(8))) short bfrag;   // 8 bf16 = 4 VGPR (MFMA A/B frag)
typedef __attribute__((ext_vector_type(4))) float ffrag;   // 4 f32 (MFMA C/D frag)
typedef __attribute__((ext_vector_type(4))) float f32x4v;

// RNE float -> bf16 (bit math; matches numpy/JAX round-to-nearest-even)
__device__ __forceinline__ u16 f2bf(float f) {
  unsigned u = __float_as_uint(f);
  u += 0x7FFFu + ((u >> 16) & 1u);
  return (u16)(u >> 16);
}
__device__ __forceinline__ float bf2f(u16 u) {
  return __uint_as_float(((unsigned)u) << 16);
}

// async global->LDS, 16B per lane (wave-uniform LDS base + lane*16)
#define GLDS16(g, l)                                                  \
  __builtin_amdgcn_global_load_lds(                                   \
      (__attribute__((address_space(1))) const void*)(g),             \
      (__attribute__((address_space(3))) void*)(l), 16, 0, 0)

#define MEMFENCE() asm volatile("" ::: "memory")

// ---------------- split: f32 -> (bf16 hi, bf16 lo) ----------------
__global__ void __launch_bounds__(256) split_bf16_kernel(
    const float* __restrict__ in, u16* __restrict__ hi,
    u16* __restrict__ lo, long n4) {
  long i = (long)blockIdx.x * blockDim.x + threadIdx.x;
  const long stride = (long)gridDim.x * blockDim.x;
  for (; i < n4; i += stride) {
    f32x4v v = reinterpret_cast<const f32x4v*>(in)[i];
    u16 h[4], l[4];
#pragma unroll
    for (int j = 0; j < 4; ++j) {
      float f = v[j];
      u16 hb = f2bf(f);
      h[j] = hb;
      l[j] = f2bf(f - bf2f(hb));
    }
    ushort4 hv, lv;
    hv.x = h[0]; hv.y = h[1]; hv.z = h[2]; hv.w = h[3];
    lv.x = l[0]; lv.y = l[1]; lv.z = l[2]; lv.w = l[3];
    reinterpret_cast<ushort4*>(hi)[i] = hv;
    reinterpret_cast<ushort4*>(lo)[i] = lv;
  }
}

// ---------------- transpose f32 [R][C] -> bf16 [C][R] ----------------
__global__ void __launch_bounds__(256) transpose_bf16_kernel(
    const float* __restrict__ in, u16* __restrict__ out, int R, int C) {
  __shared__ u16 tile[64][65];
  const int bc = blockIdx.x << 6;
  const int br = blockIdx.y << 6;
  const int tc = threadIdx.x & 63;
  const int tr0 = threadIdx.x >> 6;
#pragma unroll
  for (int p = 0; p < 16; ++p) {
    int r = tr0 + (p << 2);
    tile[tc][r] = f2bf(in[(size_t)(br + r) * C + (bc + tc)]);
  }
  __syncthreads();
#pragma unroll
  for (int p = 0; p < 16; ++p) {
    int orow = tr0 + (p << 2);
    out[(size_t)(bc + orow) * R + (br + tc)] = tile[orow][tc];
  }
}

// ================= 256^2 8-phase GEMM  C = sum_seg A_seg * B_seg^T =========
// NSEG==1: A0*B0^T. NSEG==3: x_hi*p_hi + x_lo*p_hi + x_hi*p_lo via K-concat
// (tile tau: seg=tau>>6 selects pointers). BK=64, 8 waves (2M x 4N),
// per-wave C = 128x64. LDS: 2 buf x (A 32KB + B 32KB).
//
// Phase schedule (k-slice-major, balanced 8/4/8/4 ds_reads):
//   p0: read A[0..3][s0]+B[*][s0], MFMA m0-3 x s0 ; stage A0[t+1]
//   p1: read A[4..7][s0],          MFMA m4-7 x s0 ; stage A1[t+1]
//   p2: read A[0..3][s1]+B[*][s1], MFMA m0-3 x s1 ; (no stage)
//   p3: read A[4..7][s1],          MFMA m4-7 x s1 ; stage B0,B1[t+2]
// Overwrite map: A[b] last read p3 -> A[t+1] staged p0/p1 of next tile (safe);
// B[b] last read p2 -> B[t+2] staged p3 (barrier-separated). Tile-end
// vmcnt(4) (only B[t+2] = 4 instrs in flight); vmcnt(0) at t==NT-2.
// LDS swizzle: slot XOR ((row&7) over byte bits 4-6), both-sides (inverse-
// swizzled global source for the linear global_load_lds dest + swizzled
// ds_read addresses).
template <int NSEG, bool QUANT>
__global__ void __launch_bounds__(512, 2) gemm256_kernel(
    const u16* __restrict__ A0, const u16* __restrict__ A1,
    const u16* __restrict__ B0, const u16* __restrict__ B1,
    void* __restrict__ Cout, const float* __restrict__ cent,
    int M, int N) {
  constexpr int NT = NSEG * 64;  // K-tiles of 64
  __shared__ __align__(16) char SM[131072];
  __shared__ float clut[16];
  const int tid = threadIdx.x;
  if (QUANT && tid < 16) clut[tid] = cent[tid];

  // XCD swizzle (nwg = 512, %8==0 -> bijective)
  const int nbn = N >> 8;
  const int nwg = (M >> 8) * nbn;
  int wg = blockIdx.x;
  wg = (wg & 7) * (nwg >> 3) + (wg >> 3);
  const int tm = (wg / nbn) << 8;
  const int tn = (wg % nbn) << 8;

  const int lane = tid & 63;
  const int wv = tid >> 6;
  const int wm = wv >> 2;   // 0..1 : A-half / row group
  const int wn = wv & 3;    // 0..3 : 64-col group
  const int l15 = lane & 15;
  const int kslc = lane >> 4;          // 0..3
  const int cXor = (lane & 7) << 4;    // swizzle XOR for ds_read

  // staging per-thread global offset (elements): row = wv*8 + (lane>>3),
  // col pre-swizzled so linear LDS dest ends up swizzled.
  const size_t thrOff =
      (size_t)(wv * 8 + (lane >> 3)) * 4096 + 8 * ((lane & 7) ^ (lane >> 3));
  const int ldsThr = wv * 1024 + lane * 16;  // bytes within a 16KB half

  // kind: 0=A0-half, 1=A1-half, 2=B0-half, 3=B1-half of K-tile tau
  auto STAGE = [&](int kind, int tau) {
    if (tau >= NT) return;
    const int b = tau & 1;
    const int seg = (NSEG == 3) ? (tau >> 6) : 0;
    const size_t ktE = (size_t)(tau & 63) * 64;
    const u16* src;
    char* lds;
    if (kind >= 2) {
      const u16* bbase = (NSEG == 3 && seg == 2) ? B1 : B0;
      const int idx = kind - 2;
      src = bbase + (size_t)(tn + idx * 128) * 4096 + ktE + thrOff;
      lds = SM + b * 65536 + 32768 + idx * 16384 + ldsThr;
    } else {
      const u16* abase = (NSEG == 3 && seg == 1) ? A1 : A0;
      src = abase + (size_t)(tm + kind * 128) * 4096 + ktE + thrOff;
      lds = SM + b * 65536 + kind * 16384 + ldsThr;
    }
    GLDS16(src, lds);
    GLDS16(src + 262144, lds + 8192);  // +64 rows
  };

// ds_read byte address within arena (swizzled)
#define LDSA(b, f, s)                                                      \
  (*reinterpret_cast<const bfrag*>(                                        \
      SM + (b) * 65536 + wm * 16384 + (((f) * 16 + l15) << 7) +            \
      ((((s) << 6) | (kslc << 4)) ^ cXor)))
#define LDSB(b, f, s)                                                      \
  (*reinterpret_cast<const bfrag*>(                                        \
      SM + (b) * 65536 + 32768 + (wn >> 1) * 16384 +                       \
      ((((wn & 1) * 64) + (f) * 16 + l15) << 7) +                          \
      ((((s) << 6) | (kslc << 4)) ^ cXor)))

  ffrag acc[8][4];
#pragma unroll
  for (int m = 0; m < 8; ++m)
#pragma unroll
    for (int n = 0; n < 4; ++n) acc[m][n] = {0.f, 0.f, 0.f, 0.f};

  // prologue: tile0 complete + B halves of tile1 (B staged 2 tiles ahead)
  STAGE(0, 0); STAGE(1, 0); STAGE(2, 0); STAGE(3, 0);
  STAGE(2, 1); STAGE(3, 1);
  asm volatile("s_waitcnt vmcnt(4)" ::: "memory");  // tile 0 landed
  MEMFENCE();
  __builtin_amdgcn_s_barrier();

  bfrag Af[4], Bf[4];

  for (int t = 0; t < NT; ++t) {
    const int b = t & 1;
#pragma unroll
    for (int p = 0; p < 4; ++p) {
      const int s = p >> 1;        // k-slice of this phase
      const int mb = (p & 1) * 4;  // m-base of this phase
      // ---- ds-load register subtiles (8 or 4 x ds_read_b128)
      if ((p & 1) == 0) {
#pragma unroll
        for (int n = 0; n < 4; ++n) Bf[n] = LDSB(b, n, s);
      }
#pragma unroll
      for (int m = 0; m < 4; ++m) Af[m] = LDSA(b, mb + m, s);
      // ---- stage (targets drained at a barrier-separated earlier phase)
      if (p == 0) STAGE(0, t + 1);
      else if (p == 1) STAGE(1, t + 1);
      else if (p == 3) { STAGE(2, t + 2); STAGE(3, t + 2); }
      MEMFENCE();
      __builtin_amdgcn_s_barrier();
      asm volatile("s_waitcnt lgkmcnt(0)" ::: "memory");
      __builtin_amdgcn_s_setprio(1);
#pragma unroll
      for (int m = 0; m < 4; ++m)
#pragma unroll
        for (int n = 0; n < 4; ++n)
          acc[mb + m][n] = __builtin_amdgcn_mfma_f32_16x16x32_bf16(
              Af[m], Bf[n], acc[mb + m][n], 0, 0, 0);
      __builtin_amdgcn_s_setprio(0);
      if (p == 3) {
        // counted vmcnt before the tile-end barrier (per-wave counter)
        if (t == NT - 2)
          asm volatile("s_waitcnt vmcnt(0)" ::: "memory");
        else if (t < NT - 2)
          asm volatile("s_waitcnt vmcnt(4)" ::: "memory");
      }
      MEMFENCE();
      __builtin_amdgcn_s_barrier();
    }
  }

  // epilogue; C/D frag mapping: col = lane&15, row = (lane>>4)*4 + reg
  const int r0 = tm + wm * 128 + kslc * 4;
  const int c0 = tn + wn * 64 + l15;
  if constexpr (QUANT) {
    u16* Y = reinterpret_cast<u16*>(Cout);
#pragma unroll
    for (int m = 0; m < 8; ++m)
#pragma unroll
      for (int n = 0; n < 4; ++n)
#pragma unroll
        for (int r = 0; r < 4; ++r) {
          float y = acc[m][n][r];
          float s = rintf((y + 1.0f) * 7.5f);  // RNE == jnp.round
          int idx = (int)s;
          idx = idx < 0 ? 0 : (idx > 15 ? 15 : idx);
          Y[(size_t)(r0 + m * 16 + r) * N + (c0 + n * 16)] = f2bf(clut[idx]);
        }
  } else {
    float* Co = reinterpret_cast<float*>(Cout);
#pragma unroll
    for (int m = 0; m < 8; ++m)
#pragma unroll
      for (int n = 0; n < 4; ++n)
#pragma unroll
        for (int r = 0; r < 4; ++r)
          Co[(size_t)(r0 + m * 16 + r) * N + (c0 + n * 16)] = acc[m][n][r];
  }
#undef LDSA
#undef LDSB
}

extern "C" void kernel_launch(void* const* d_in, const int* in_sizes, int n_in,
                              void* d_out, int out_size, void* d_ws, size_t ws_size,
                              hipStream_t stream) {
  const float* x = (const float*)d_in[0];     // [8192][4096]
  const float* Pi = (const float*)d_in[1];    // [4096][4096]
  const float* cent = (const float*)d_in[2];  // [16]
  float* out = (float*)d_out;                 // [8192][4096]

  const size_t MB = (size_t)1 << 20;
  if (ws_size < 288 * MB) return;  // need 288MB scratch

  char* ws = (char*)d_ws;
  u16* x_hi = (u16*)(ws + 0 * MB);    // 64MB  bf16(x)
  u16* x_lo = (u16*)(ws + 64 * MB);   // 64MB  bf16(x - x_hi)
  u16* p_hi = (u16*)(ws + 128 * MB);  // 32MB  bf16(Pi)
  u16* p_lo = (u16*)(ws + 160 * MB);  // 32MB  bf16(Pi - p_hi)
  u16* piT  = (u16*)(ws + 192 * MB);  // 32MB  bf16(Pi^T)
  u16* yq   = (u16*)(ws + 224 * MB);  // 64MB  bf16(quantize(x @ Pi^T))

  split_bf16_kernel<<<2048, 256, 0, stream>>>(x, x_hi, x_lo, (long)NTOK * DD / 4);
  split_bf16_kernel<<<1024, 256, 0, stream>>>(Pi, p_hi, p_lo, (long)DD * DD / 4);
  transpose_bf16_kernel<<<dim3(DD / 64, DD / 64), 256, 0, stream>>>(Pi, piT, DD, DD);

  const int nwg = (NTOK / 256) * (DD / 256);  // 512, %8==0
  // y = x @ Pi^T  ~= x_hi*p_hi + x_lo*p_hi + x_hi*p_lo ; quantize -> yq (bf16)
  gemm256_kernel<3, true><<<nwg, 512, 0, stream>>>(
      x_hi, x_lo, p_hi, p_lo, yq, cent, NTOK, DD);
  // out = yq @ Pi  (B^T form via piT)
  gemm256_kernel<1, false><<<nwg, 512, 0, stream>>>(
      yq, nullptr, piT, nullptr, out, nullptr, NTOK, DD);
}

// Round 4
// 1096.593 us; speedup vs baseline: 1.0487x; 1.0487x over previous
//
#include <hip/hip_runtime.h>
#include <hip/hip_bf16.h>

#define DD 4096
#define NTOK 8192

using u16 = unsigned short;

typedef __attribute__((ext_vector_type(8))) short bfrag;   // 8 bf16 = 4 VGPR (MFMA A/B frag)
typedef __attribute__((ext_vector_type(4))) float ffrag;   // 4 f32 (MFMA C/D frag)
typedef __attribute__((ext_vector_type(4))) float f32x4v;

// RNE float -> bf16 (bit math; matches numpy/JAX round-to-nearest-even)
__device__ __forceinline__ u16 f2bf(float f) {
  unsigned u = __float_as_uint(f);
  u += 0x7FFFu + ((u >> 16) & 1u);
  return (u16)(u >> 16);
}
__device__ __forceinline__ float bf2f(u16 u) {
  return __uint_as_float(((unsigned)u) << 16);
}

// async global->LDS, 16B per lane (wave-uniform LDS base + lane*16)
#define GLDS16(g, l)                                                  \
  __builtin_amdgcn_global_load_lds(                                   \
      (__attribute__((address_space(1))) const void*)(g),             \
      (__attribute__((address_space(3))) void*)(l), 16, 0, 0)

#define MEMFENCE() asm volatile("" ::: "memory")

// ---------------- split: f32 -> (bf16 hi, bf16 lo) ----------------
__global__ void __launch_bounds__(256) split_bf16_kernel(
    const float* __restrict__ in, u16* __restrict__ hi,
    u16* __restrict__ lo, long n4) {
  long i = (long)blockIdx.x * blockDim.x + threadIdx.x;
  const long stride = (long)gridDim.x * blockDim.x;
  for (; i < n4; i += stride) {
    f32x4v v = reinterpret_cast<const f32x4v*>(in)[i];
    u16 h[4], l[4];
#pragma unroll
    for (int j = 0; j < 4; ++j) {
      float f = v[j];
      u16 hb = f2bf(f);
      h[j] = hb;
      l[j] = f2bf(f - bf2f(hb));
    }
    ushort4 hv, lv;
    hv.x = h[0]; hv.y = h[1]; hv.z = h[2]; hv.w = h[3];
    lv.x = l[0]; lv.y = l[1]; lv.z = l[2]; lv.w = l[3];
    reinterpret_cast<ushort4*>(hi)[i] = hv;
    reinterpret_cast<ushort4*>(lo)[i] = lv;
  }
}

// ---------------- transpose f32 [R][C] -> bf16 [C][R] ----------------
__global__ void __launch_bounds__(256) transpose_bf16_kernel(
    const float* __restrict__ in, u16* __restrict__ out, int R, int C) {
  __shared__ u16 tile[64][65];
  const int bc = blockIdx.x << 6;
  const int br = blockIdx.y << 6;
  const int tc = threadIdx.x & 63;
  const int tr0 = threadIdx.x >> 6;
#pragma unroll
  for (int p = 0; p < 16; ++p) {
    int r = tr0 + (p << 2);
    tile[tc][r] = f2bf(in[(size_t)(br + r) * C + (bc + tc)]);
  }
  __syncthreads();
#pragma unroll
  for (int p = 0; p < 16; ++p) {
    int orow = tr0 + (p << 2);
    out[(size_t)(bc + orow) * R + (br + tc)] = tile[orow][tc];
  }
}

// ================= 256^2 8-phase GEMM  C = sum_seg A_seg * B_seg^T =========
// NSEG==1: A0*B0^T. NSEG==3: x_hi*p_hi + x_lo*p_hi + x_hi*p_lo via K-concat.
// BK=64, 8 waves (2M x 4N), per-wave C = 128x64. LDS: 2buf x (A 32KB + B 32KB).
//
// SOFTWARE-PIPELINED phases: ds_reads at phase-top are for phase q+1
// (double frag sets E/O); MFMA(q) consumes frags read at q-1 whose LDS
// latency hid under MFMA(q-1). Compiler inserts counted lgkm waits for the
// frag deps; MEMFENCE+s_barrier pin the prefetch reads at phase-top.
//   p0-top: read AfO=A[4-7][s0]      | stage A0,A1[t+1] | MFMA AfE*BfE acc0-3
//   p1-top: read AfE=A[0-3][s1], BfO |                  | MFMA AfO*BfE acc4-7
//   p2-top: read AfO=A[4-7][s1]      | vmcnt(0) at end  | MFMA AfE*BfO acc0-3
//   p3-top: read AfE,BfE from t+1    | stage B0,B1[t+2] | MFMA AfO*BfO acc4-7
// Overwrite map: stage A[t+1]@p0 overwrites A[t-1], last read issued
// (t-1,p2)-top, drained before (t-1,p3)-end barrier. Stage B[t+2]@p3
// overwrites B[t], last read issued (t,p1)-top, drained before (t,p2)-end
// barrier. Cross-tile reads @p3-top (A[t+1],B[t+1]) covered by vmcnt(0) at
// (t,p2)-end + barrier (all in-flight stages are 1-3 phases old).
// LDS swizzle: 3-bit slot XOR ((lane&7)<<4), both-sides (inverse-swizzled
// global source + swizzled ds_read addresses). Verified 0 bank conflicts.
template <int NSEG, bool QUANT>
__global__ void __launch_bounds__(512, 2) gemm256_kernel(
    const u16* __restrict__ A0, const u16* __restrict__ A1,
    const u16* __restrict__ B0, const u16* __restrict__ B1,
    void* __restrict__ Cout, const float* __restrict__ cent,
    int M, int N) {
  constexpr int NT = NSEG * 64;  // K-tiles of 64
  __shared__ __align__(16) char SM[131072];
  __shared__ float clut[16];
  const int tid = threadIdx.x;
  if (QUANT && tid < 16) clut[tid] = cent[tid];

  // XCD swizzle (nwg = 512, %8==0 -> bijective)
  const int nbn = N >> 8;
  const int nwg = (M >> 8) * nbn;
  int wg = blockIdx.x;
  wg = (wg & 7) * (nwg >> 3) + (wg >> 3);
  const int tm = (wg / nbn) << 8;
  const int tn = (wg % nbn) << 8;

  const int lane = tid & 63;
  const int wv = tid >> 6;
  const int wm = wv >> 2;   // 0..1 : A row-panel
  const int wn = wv & 3;    // 0..3 : 64-col group
  const int l15 = lane & 15;
  const int kslc = lane >> 4;          // 0..3
  const int cXor = (lane & 7) << 4;    // swizzle XOR for ds_read

  // staging per-thread global offset (elements): row = wv*8 + (lane>>3),
  // col pre-swizzled so linear LDS dest ends up swizzled.
  const size_t thrOff =
      (size_t)(wv * 8 + (lane >> 3)) * 4096 + 8 * ((lane & 7) ^ (lane >> 3));
  const int ldsThr = wv * 1024 + lane * 16;  // bytes within a 16KB half

  // kind: 0=A0-half, 1=A1-half, 2=B0-half, 3=B1-half of K-tile tau
  auto STAGE = [&](int kind, int tau) {
    if (tau >= NT) return;
    const int b = tau & 1;
    const int seg = (NSEG == 3) ? (tau >> 6) : 0;
    const size_t ktE = (size_t)(tau & 63) * 64;
    const u16* src;
    char* lds;
    if (kind >= 2) {
      const u16* bbase = (NSEG == 3 && seg == 2) ? B1 : B0;
      const int idx = kind - 2;
      src = bbase + (size_t)(tn + idx * 128) * 4096 + ktE + thrOff;
      lds = SM + b * 65536 + 32768 + idx * 16384 + ldsThr;
    } else {
      const u16* abase = (NSEG == 3 && seg == 1) ? A1 : A0;
      src = abase + (size_t)(tm + kind * 128) * 4096 + ktE + thrOff;
      lds = SM + b * 65536 + kind * 16384 + ldsThr;
    }
    GLDS16(src, lds);
    GLDS16(src + 262144, lds + 8192);  // +64 rows
  };

// ds_read byte address within arena (swizzled)
#define LDSA(b, f, s)                                                      \
  (*reinterpret_cast<const bfrag*>(                                        \
      SM + (b) * 65536 + wm * 16384 + (((f) * 16 + l15) << 7) +            \
      ((((s) << 6) | (kslc << 4)) ^ cXor)))
#define LDSB(b, f, s)                                                      \
  (*reinterpret_cast<const bfrag*>(                                        \
      SM + (b) * 65536 + 32768 + (wn >> 1) * 16384 +                       \
      ((((wn & 1) * 64) + (f) * 16 + l15) << 7) +                          \
      ((((s) << 6) | (kslc << 4)) ^ cXor)))

#define MFMA16(Aset, Bset, mb)                                             \
  __builtin_amdgcn_s_setprio(1);                                           \
  _Pragma("unroll")                                                        \
  for (int m = 0; m < 4; ++m)                                              \
    _Pragma("unroll")                                                      \
    for (int n = 0; n < 4; ++n)                                            \
      acc[(mb) + m][n] = __builtin_amdgcn_mfma_f32_16x16x32_bf16(          \
          Aset[m], Bset[n], acc[(mb) + m][n], 0, 0, 0);                    \
  __builtin_amdgcn_s_setprio(0);

  ffrag acc[8][4];
#pragma unroll
  for (int m = 0; m < 8; ++m)
#pragma unroll
    for (int n = 0; n < 4; ++n) acc[m][n] = {0.f, 0.f, 0.f, 0.f};

  bfrag AfE[4], AfO[4], BfE[4], BfO[4];

  // prologue: stage tile0 (A+B) and B[1]; wait tile0; preload p0 frags
  STAGE(0, 0); STAGE(1, 0); STAGE(2, 0); STAGE(3, 0);
  STAGE(2, 1); STAGE(3, 1);
  asm volatile("s_waitcnt vmcnt(4)" ::: "memory");
  MEMFENCE();
  __builtin_amdgcn_s_barrier();
#pragma unroll
  for (int m = 0; m < 4; ++m) AfE[m] = LDSA(0, m, 0);
#pragma unroll
  for (int n = 0; n < 4; ++n) BfE[n] = LDSB(0, n, 0);

  for (int t = 0; t < NT; ++t) {
    const int b = t & 1;
    // ---------- phase 0 ----------
#pragma unroll
    for (int m = 0; m < 4; ++m) AfO[m] = LDSA(b, 4 + m, 0);
    STAGE(0, t + 1); STAGE(1, t + 1);
    MEMFENCE();
    __builtin_amdgcn_s_barrier();
    MFMA16(AfE, BfE, 0)
    MEMFENCE();
    __builtin_amdgcn_s_barrier();
    // ---------- phase 1 ----------
#pragma unroll
    for (int m = 0; m < 4; ++m) AfE[m] = LDSA(b, m, 1);
#pragma unroll
    for (int n = 0; n < 4; ++n) BfO[n] = LDSB(b, n, 1);
    MEMFENCE();
    __builtin_amdgcn_s_barrier();
    MFMA16(AfO, BfE, 4)
    MEMFENCE();
    __builtin_amdgcn_s_barrier();
    // ---------- phase 2 ----------
#pragma unroll
    for (int m = 0; m < 4; ++m) AfO[m] = LDSA(b, 4 + m, 1);
    MEMFENCE();
    __builtin_amdgcn_s_barrier();
    MFMA16(AfE, BfO, 0)
    // all outstanding stages (B[t+1]: 3 phases old, A[t+1]: 2 phases old)
    // must land before the p3-top cross-tile reads
    asm volatile("s_waitcnt vmcnt(0)" ::: "memory");
    MEMFENCE();
    __builtin_amdgcn_s_barrier();
    // ---------- phase 3 ----------
    if (t + 1 < NT) {
#pragma unroll
      for (int m = 0; m < 4; ++m) AfE[m] = LDSA(b ^ 1, m, 0);
#pragma unroll
      for (int n = 0; n < 4; ++n) BfE[n] = LDSB(b ^ 1, n, 0);
    }
    STAGE(2, t + 2); STAGE(3, t + 2);
    MEMFENCE();
    __builtin_amdgcn_s_barrier();
    MFMA16(AfO, BfO, 4)
    MEMFENCE();
    __builtin_amdgcn_s_barrier();
  }

  // epilogue; C/D frag mapping: col = lane&15, row = (lane>>4)*4 + reg
  const int r0 = tm + wm * 128 + kslc * 4;
  const int c0 = tn + wn * 64 + l15;
  if constexpr (QUANT) {
    u16* Y = reinterpret_cast<u16*>(Cout);
#pragma unroll
    for (int m = 0; m < 8; ++m)
#pragma unroll
      for (int n = 0; n < 4; ++n)
#pragma unroll
        for (int r = 0; r < 4; ++r) {
          float y = acc[m][n][r];
          float s = rintf((y + 1.0f) * 7.5f);  // RNE == jnp.round
          int idx = (int)s;
          idx = idx < 0 ? 0 : (idx > 15 ? 15 : idx);
          Y[(size_t)(r0 + m * 16 + r) * N + (c0 + n * 16)] = f2bf(clut[idx]);
        }
  } else {
    float* Co = reinterpret_cast<float*>(Cout);
#pragma unroll
    for (int m = 0; m < 8; ++m)
#pragma unroll
      for (int n = 0; n < 4; ++n)
#pragma unroll
        for (int r = 0; r < 4; ++r)
          Co[(size_t)(r0 + m * 16 + r) * N + (c0 + n * 16)] = acc[m][n][r];
  }
#undef LDSA
#undef LDSB
#undef MFMA16
}

extern "C" void kernel_launch(void* const* d_in, const int* in_sizes, int n_in,
                              void* d_out, int out_size, void* d_ws, size_t ws_size,
                              hipStream_t stream) {
  const float* x = (const float*)d_in[0];     // [8192][4096]
  const float* Pi = (const float*)d_in[1];    // [4096][4096]
  const float* cent = (const float*)d_in[2];  // [16]
  float* out = (float*)d_out;                 // [8192][4096]

  const size_t MB = (size_t)1 << 20;
  if (ws_size < 288 * MB) return;  // need 288MB scratch

  char* ws = (char*)d_ws;
  u16* x_hi = (u16*)(ws + 0 * MB);    // 64MB  bf16(x)
  u16* x_lo = (u16*)(ws + 64 * MB);   // 64MB  bf16(x - x_hi)
  u16* p_hi = (u16*)(ws + 128 * MB);  // 32MB  bf16(Pi)
  u16* p_lo = (u16*)(ws + 160 * MB);  // 32MB  bf16(Pi - p_hi)
  u16* piT  = (u16*)(ws + 192 * MB);  // 32MB  bf16(Pi^T)
  u16* yq   = (u16*)(ws + 224 * MB);  // 64MB  bf16(quantize(x @ Pi^T))

  split_bf16_kernel<<<2048, 256, 0, stream>>>(x, x_hi, x_lo, (long)NTOK * DD / 4);
  split_bf16_kernel<<<1024, 256, 0, stream>>>(Pi, p_hi, p_lo, (long)DD * DD / 4);
  transpose_bf16_kernel<<<dim3(DD / 64, DD / 64), 256, 0, stream>>>(Pi, piT, DD, DD);

  const int nwg = (NTOK / 256) * (DD / 256);  // 512, %8==0
  // y = x @ Pi^T  ~= x_hi*p_hi + x_lo*p_hi + x_hi*p_lo ; quantize -> yq (bf16)
  gemm256_kernel<3, true><<<nwg, 512, 0, stream>>>(
      x_hi, x_lo, p_hi, p_lo, yq, cent, NTOK, DD);
  // out = yq @ Pi  (B^T form via piT)
  gemm256_kernel<1, false><<<nwg, 512, 0, stream>>>(
      yq, nullptr, piT, nullptr, out, nullptr, NTOK, DD);
}

// Round 5
// 1023.279 us; speedup vs baseline: 1.1239x; 1.0716x over previous
//
#include <hip/hip_runtime.h>
#include <hip/hip_bf16.h>

#define DD 4096
#define NTOK 8192

using u16 = unsigned short;

typedef __attribute__((ext_vector_type(8))) short bfrag;   // 8 bf16 = 4 VGPR
typedef __attribute__((ext_vector_type(4))) float ffrag;   // 4 f32 (MFMA C/D)
typedef __attribute__((ext_vector_type(4))) float f32x4v;

// RNE float -> bf16 (bit math; matches numpy/JAX round-to-nearest-even)
__device__ __forceinline__ u16 f2bf(float f) {
  unsigned u = __float_as_uint(f);
  u += 0x7FFFu + ((u >> 16) & 1u);
  return (u16)(u >> 16);
}
__device__ __forceinline__ float bf2f(u16 u) {
  return __uint_as_float(((unsigned)u) << 16);
}

#define GLDS16(g, l)                                                  \
  __builtin_amdgcn_global_load_lds(                                   \
      (__attribute__((address_space(1))) const void*)(g),             \
      (__attribute__((address_space(3))) void*)(l), 16, 0, 0)

#define MEMFENCE() asm volatile("" ::: "memory")

// ---------------- split: f32 -> (bf16 hi, bf16 lo) ----------------
__global__ void __launch_bounds__(256) split_bf16_kernel(
    const float* __restrict__ in, u16* __restrict__ hi,
    u16* __restrict__ lo, long n4) {
  long i = (long)blockIdx.x * blockDim.x + threadIdx.x;
  const long stride = (long)gridDim.x * blockDim.x;
  for (; i < n4; i += stride) {
    f32x4v v = reinterpret_cast<const f32x4v*>(in)[i];
    u16 h[4], l[4];
#pragma unroll
    for (int j = 0; j < 4; ++j) {
      float f = v[j];
      u16 hb = f2bf(f);
      h[j] = hb;
      l[j] = f2bf(f - bf2f(hb));
    }
    ushort4 hv, lv;
    hv.x = h[0]; hv.y = h[1]; hv.z = h[2]; hv.w = h[3];
    lv.x = l[0]; lv.y = l[1]; lv.z = l[2]; lv.w = l[3];
    reinterpret_cast<ushort4*>(hi)[i] = hv;
    reinterpret_cast<ushort4*>(lo)[i] = lv;
  }
}

// ---------------- transpose f32 [R][C] -> bf16 [C][R] ----------------
__global__ void __launch_bounds__(256) transpose_bf16_kernel(
    const float* __restrict__ in, u16* __restrict__ out, int R, int C) {
  __shared__ u16 tile[64][65];
  const int bc = blockIdx.x << 6;
  const int br = blockIdx.y << 6;
  const int tc = threadIdx.x & 63;
  const int tr0 = threadIdx.x >> 6;
#pragma unroll
  for (int p = 0; p < 16; ++p) {
    int r = tr0 + (p << 2);
    tile[tc][r] = f2bf(in[(size_t)(br + r) * C + (bc + tc)]);
  }
  __syncthreads();
#pragma unroll
  for (int p = 0; p < 16; ++p) {
    int orow = tr0 + (p << 2);
    out[(size_t)(bc + orow) * R + (br + tc)] = tile[orow][tc];
  }
}

// ============ FUSED 3-term GEMM1:  yq = quant( xh*ph^T + xl*ph^T + xh*pl^T )
// BK=32, 128 K-tiles. Per tile stage 4 units {Ah,Al,Bh,Bl} (16KB each,
// 256 rows x 32 k), LDS = 2buf x 64KB. 8 waves (2Mx4N), per-wave C=128x64.
// 5 phases/tile (16,16,16,16,32 MFMA): hh(m0-3), hh(m4-7), lh(m0-3),
// lh(m4-7), hl(all m). Ah frags (read P0/P1) are register-reused at P4;
// Bh reused P0-P3. 24 ds_read_b128 + 8 global_load_lds per tile per thread-
// group vs 128 MFMA*0.75 -- 1/3 less LDS+staging traffic than K-concat, and
// each input matrix streamed exactly once per wg (HBM fetch ~halves).
// Swizzle (BK=32, 64B rows pair-packed): byte ^= ((byte>>7)&7)<<4, applied
// to ds_read addr + inverse-applied to global source (linear gload_lds dest).
// Wave-group read pattern verified exactly 2-way bank aliasing (free, m136).
// Overwrite map: stages only at P0 (Ah,Al[t+1]) and P1 (Bh,Bl[t+1]); every
// target's last ds_read drained >=2 barriers earlier. RAW: single vmcnt(0)
// at P4-end (before tile-end barrier) drains loads issued 3-4 phases prior.
__global__ void __launch_bounds__(512, 2) gemm_fused3_kernel(
    const u16* __restrict__ Ah_, const u16* __restrict__ Al_,
    const u16* __restrict__ Bh_, const u16* __restrict__ Bl_,
    u16* __restrict__ Yq, const float* __restrict__ cent, int M, int N) {
  __shared__ __align__(16) char SM[131072];
  __shared__ float clut[16];
  const int tid = threadIdx.x;
  if (tid < 16) clut[tid] = cent[tid];

  // XCD swizzle (nwg=512, %8==0 -> bijective)
  const int nbn = N >> 8;
  const int nwg = (M >> 8) * nbn;
  int wg = blockIdx.x;
  wg = (wg & 7) * (nwg >> 3) + (wg >> 3);
  const int tm = (wg / nbn) << 8;
  const int tn = (wg % nbn) << 8;

  const int lane = tid & 63;
  const int wv = tid >> 6;
  const int wm = wv >> 2;  // 0..1
  const int wn = wv & 3;   // 0..3
  const int l15 = lane & 15;
  const int kslc = lane >> 4;

  // staging: dest D linear, source pre-unswizzled (involution S)
  const int Dst = tid * 16;
  const int Lg = Dst ^ (((Dst >> 7) & 7) << 4);
  const int srow = Lg >> 6;        // 0..127 (+128 for 2nd load)
  const int scol = (Lg & 63) >> 1; // element col: 0/8/16/24
  const size_t sOffA = (size_t)(tm + srow) * 4096 + scol;
  const size_t sOffB = (size_t)(tn + srow) * 4096 + scol;

  // u: 0=Ah 1=Al 2=Bh 3=Bl (literal at every call site -> folds)
  auto STAGE = [&](int u, const u16* base, int tau) {
    if (tau >= 128) return;
    const u16* src = base + (u < 2 ? sOffA : sOffB) + tau * 32;
    char* lds = SM + (tau & 1) * 65536 + u * 16384 + Dst;
    GLDS16(src, lds);
    GLDS16(src + (size_t)128 * 4096, lds + 8192);
  };

  // frag read offsets: element (r,k): byte r*64+k*2, swizzled.
  // slot is f-independent; byte(f) = base + f*1024.
  const int slot16 = ((((l15 & 1) << 2) | kslc) ^ (l15 >> 1)) << 4;
  const int aOff = wm * 8192 + (l15 >> 1) * 128 + slot16;
  const int bOff = wn * 4096 + (l15 >> 1) * 128 + slot16;

#define LDSF(b, ubase, off, f)                                           \
  (*reinterpret_cast<const bfrag*>(SM + (b) * 65536 + (ubase) + (off) +  \
                                   (f) * 1024))

  ffrag acc[8][4];
#pragma unroll
  for (int m = 0; m < 8; ++m)
#pragma unroll
    for (int n = 0; n < 4; ++n) acc[m][n] = {0.f, 0.f, 0.f, 0.f};

  bfrag Ahf[8], Alf[4], Bhf[4], Blf[4];

  // prologue: stage tile 0 fully
  STAGE(0, Ah_, 0); STAGE(1, Al_, 0); STAGE(2, Bh_, 0); STAGE(3, Bl_, 0);
  asm volatile("s_waitcnt vmcnt(0)" ::: "memory");
  MEMFENCE();
  __builtin_amdgcn_s_barrier();

#define MFMA16(Aset, a0, Bset, mb)                                       \
  __builtin_amdgcn_s_setprio(1);                                         \
  _Pragma("unroll")                                                      \
  for (int m = 0; m < 4; ++m)                                            \
    _Pragma("unroll")                                                    \
    for (int n = 0; n < 4; ++n)                                          \
      acc[(mb) + m][n] = __builtin_amdgcn_mfma_f32_16x16x32_bf16(        \
          Aset[(a0) + m], Bset[n], acc[(mb) + m][n], 0, 0, 0);           \
  __builtin_amdgcn_s_setprio(0);

  for (int t = 0; t < 128; ++t) {
    const int b = t & 1;
    // ---- P0: read Ah[0-3], Bh; stage Ah,Al[t+1]; MFMA hh m0-3
#pragma unroll
    for (int f = 0; f < 4; ++f) Ahf[f] = LDSF(b, 0, aOff, f);
#pragma unroll
    for (int f = 0; f < 4; ++f) Bhf[f] = LDSF(b, 32768, bOff, f);
    STAGE(0, Ah_, t + 1); STAGE(1, Al_, t + 1);
    MEMFENCE();
    __builtin_amdgcn_s_barrier();
    asm volatile("s_waitcnt lgkmcnt(0)" ::: "memory");
    MFMA16(Ahf, 0, Bhf, 0)
    MEMFENCE();
    __builtin_amdgcn_s_barrier();
    // ---- P1: read Ah[4-7]; stage Bh,Bl[t+1]; MFMA hh m4-7
#pragma unroll
    for (int f = 0; f < 4; ++f) Ahf[4 + f] = LDSF(b, 0, aOff, 4 + f);
    STAGE(2, Bh_, t + 1); STAGE(3, Bl_, t + 1);
    MEMFENCE();
    __builtin_amdgcn_s_barrier();
    asm volatile("s_waitcnt lgkmcnt(0)" ::: "memory");
    MFMA16(Ahf, 4, Bhf, 4)
    MEMFENCE();
    __builtin_amdgcn_s_barrier();
    // ---- P2: read Al[0-3]; MFMA lh m0-3
#pragma unroll
    for (int f = 0; f < 4; ++f) Alf[f] = LDSF(b, 16384, aOff, f);
    MEMFENCE();
    __builtin_amdgcn_s_barrier();
    asm volatile("s_waitcnt lgkmcnt(0)" ::: "memory");
    MFMA16(Alf, 0, Bhf, 0)
    MEMFENCE();
    __builtin_amdgcn_s_barrier();
    // ---- P3: read Al[4-7]; MFMA lh m4-7
#pragma unroll
    for (int f = 0; f < 4; ++f) Alf[f] = LDSF(b, 16384, aOff, 4 + f);
    MEMFENCE();
    __builtin_amdgcn_s_barrier();
    asm volatile("s_waitcnt lgkmcnt(0)" ::: "memory");
    MFMA16(Alf, 0, Bhf, 4)
    MEMFENCE();
    __builtin_amdgcn_s_barrier();
    // ---- P4: read Bl; MFMA hl all m (32, Ah register-reuse); vmcnt(0)
#pragma unroll
    for (int f = 0; f < 4; ++f) Blf[f] = LDSF(b, 49152, bOff, f);
    MEMFENCE();
    __builtin_amdgcn_s_barrier();
    asm volatile("s_waitcnt lgkmcnt(0)" ::: "memory");
    MFMA16(Ahf, 0, Blf, 0)
    MFMA16(Ahf, 4, Blf, 4)
    // drain next tile's stages (issued 3-4 phases ago) before end barrier
    asm volatile("s_waitcnt vmcnt(0)" ::: "memory");
    MEMFENCE();
    __builtin_amdgcn_s_barrier();
  }

  // quant epilogue; C/D mapping: col = lane&15, row = (lane>>4)*4 + reg
  const int r0 = tm + wm * 128 + kslc * 4;
  const int c0 = tn + wn * 64 + l15;
#pragma unroll
  for (int m = 0; m < 8; ++m)
#pragma unroll
    for (int n = 0; n < 4; ++n)
#pragma unroll
      for (int r = 0; r < 4; ++r) {
        float y = acc[m][n][r];
        float s = rintf((y + 1.0f) * 7.5f);  // RNE == jnp.round
        int idx = (int)s;
        idx = idx < 0 ? 0 : (idx > 15 ? 15 : idx);
        Yq[(size_t)(r0 + m * 16 + r) * N + (c0 + n * 16)] = f2bf(clut[idx]);
      }
#undef LDSF
#undef MFMA16
}

// ============ GEMM2 (R3 4-phase template, NSEG=1): out = yq @ Pi ==========
__global__ void __launch_bounds__(512, 2) gemm256_bt_kernel(
    const u16* __restrict__ A0, const u16* __restrict__ B0,
    float* __restrict__ Cout, int M, int N) {
  constexpr int NT = 64;
  __shared__ __align__(16) char SM[131072];
  const int tid = threadIdx.x;

  const int nbn = N >> 8;
  const int nwg = (M >> 8) * nbn;
  int wg = blockIdx.x;
  wg = (wg & 7) * (nwg >> 3) + (wg >> 3);
  const int tm = (wg / nbn) << 8;
  const int tn = (wg % nbn) << 8;

  const int lane = tid & 63;
  const int wv = tid >> 6;
  const int wm = wv >> 2;
  const int wn = wv & 3;
  const int l15 = lane & 15;
  const int kslc = lane >> 4;
  const int cXor = (lane & 7) << 4;

  const size_t thrOff =
      (size_t)(wv * 8 + (lane >> 3)) * 4096 + 8 * ((lane & 7) ^ (lane >> 3));
  const int ldsThr = wv * 1024 + lane * 16;

  auto STAGE = [&](int kind, int tau) {
    if (tau >= NT) return;
    const int b = tau & 1;
    const size_t ktE = (size_t)tau * 64;
    const u16* src;
    char* lds;
    if (kind >= 2) {
      const int idx = kind - 2;
      src = B0 + (size_t)(tn + idx * 128) * 4096 + ktE + thrOff;
      lds = SM + b * 65536 + 32768 + idx * 16384 + ldsThr;
    } else {
      src = A0 + (size_t)(tm + kind * 128) * 4096 + ktE + thrOff;
      lds = SM + b * 65536 + kind * 16384 + ldsThr;
    }
    GLDS16(src, lds);
    GLDS16(src + 262144, lds + 8192);
  };

#define LDSA(b, f, s)                                                      \
  (*reinterpret_cast<const bfrag*>(                                        \
      SM + (b) * 65536 + wm * 16384 + (((f) * 16 + l15) << 7) +            \
      ((((s) << 6) | (kslc << 4)) ^ cXor)))
#define LDSB(b, f, s)                                                      \
  (*reinterpret_cast<const bfrag*>(                                        \
      SM + (b) * 65536 + 32768 + (wn >> 1) * 16384 +                       \
      ((((wn & 1) * 64) + (f) * 16 + l15) << 7) +                          \
      ((((s) << 6) | (kslc << 4)) ^ cXor)))

  ffrag acc[8][4];
#pragma unroll
  for (int m = 0; m < 8; ++m)
#pragma unroll
    for (int n = 0; n < 4; ++n) acc[m][n] = {0.f, 0.f, 0.f, 0.f};

  STAGE(0, 0); STAGE(1, 0); STAGE(2, 0); STAGE(3, 0);
  STAGE(2, 1); STAGE(3, 1);
  asm volatile("s_waitcnt vmcnt(4)" ::: "memory");
  MEMFENCE();
  __builtin_amdgcn_s_barrier();

  bfrag Af[4], Bf[4];

  for (int t = 0; t < NT; ++t) {
    const int b = t & 1;
#pragma unroll
    for (int p = 0; p < 4; ++p) {
      const int s = p >> 1;
      const int mb = (p & 1) * 4;
      if ((p & 1) == 0) {
#pragma unroll
        for (int n = 0; n < 4; ++n) Bf[n] = LDSB(b, n, s);
      }
#pragma unroll
      for (int m = 0; m < 4; ++m) Af[m] = LDSA(b, mb + m, s);
      if (p == 0) STAGE(0, t + 1);
      else if (p == 1) STAGE(1, t + 1);
      else if (p == 3) { STAGE(2, t + 2); STAGE(3, t + 2); }
      MEMFENCE();
      __builtin_amdgcn_s_barrier();
      asm volatile("s_waitcnt lgkmcnt(0)" ::: "memory");
      __builtin_amdgcn_s_setprio(1);
#pragma unroll
      for (int m = 0; m < 4; ++m)
#pragma unroll
        for (int n = 0; n < 4; ++n)
          acc[mb + m][n] = __builtin_amdgcn_mfma_f32_16x16x32_bf16(
              Af[m], Bf[n], acc[mb + m][n], 0, 0, 0);
      __builtin_amdgcn_s_setprio(0);
      if (p == 3) {
        if (t == NT - 2)
          asm volatile("s_waitcnt vmcnt(0)" ::: "memory");
        else if (t < NT - 2)
          asm volatile("s_waitcnt vmcnt(4)" ::: "memory");
      }
      MEMFENCE();
      __builtin_amdgcn_s_barrier();
    }
  }

  const int r0 = tm + wm * 128 + kslc * 4;
  const int c0 = tn + wn * 64 + l15;
#pragma unroll
  for (int m = 0; m < 8; ++m)
#pragma unroll
    for (int n = 0; n < 4; ++n)
#pragma unroll
      for (int r = 0; r < 4; ++r)
        Cout[(size_t)(r0 + m * 16 + r) * N + (c0 + n * 16)] = acc[m][n][r];
#undef LDSA
#undef LDSB
}

extern "C" void kernel_launch(void* const* d_in, const int* in_sizes, int n_in,
                              void* d_out, int out_size, void* d_ws, size_t ws_size,
                              hipStream_t stream) {
  const float* x = (const float*)d_in[0];     // [8192][4096]
  const float* Pi = (const float*)d_in[1];    // [4096][4096]
  const float* cent = (const float*)d_in[2];  // [16]
  float* out = (float*)d_out;                 // [8192][4096]

  const size_t MB = (size_t)1 << 20;
  if (ws_size < 288 * MB) return;

  char* ws = (char*)d_ws;
  u16* x_hi = (u16*)(ws + 0 * MB);    // 64MB  bf16(x)
  u16* x_lo = (u16*)(ws + 64 * MB);   // 64MB  bf16(x - x_hi)
  u16* p_hi = (u16*)(ws + 128 * MB);  // 32MB  bf16(Pi)
  u16* p_lo = (u16*)(ws + 160 * MB);  // 32MB  bf16(Pi - p_hi)
  u16* piT  = (u16*)(ws + 192 * MB);  // 32MB  bf16(Pi^T)
  u16* yq   = (u16*)(ws + 224 * MB);  // 64MB  bf16(quantize(x @ Pi^T))

  split_bf16_kernel<<<2048, 256, 0, stream>>>(x, x_hi, x_lo, (long)NTOK * DD / 4);
  split_bf16_kernel<<<1024, 256, 0, stream>>>(Pi, p_hi, p_lo, (long)DD * DD / 4);
  transpose_bf16_kernel<<<dim3(DD / 64, DD / 64), 256, 0, stream>>>(Pi, piT, DD, DD);

  // GEMM1 fused 3-term + quantize -> yq
  gemm_fused3_kernel<<<512, 512, 0, stream>>>(
      x_hi, x_lo, p_hi, p_lo, yq, cent, NTOK, DD);
  // GEMM2: out = yq @ Pi
  gemm256_bt_kernel<<<512, 512, 0, stream>>>(yq, piT, out, NTOK, DD);
}

// Round 6
// 1014.055 us; speedup vs baseline: 1.1341x; 1.0091x over previous
//
#include <hip/hip_runtime.h>
#include <hip/hip_bf16.h>

#define DD 4096
#define NTOK 8192

using u16 = unsigned short;

typedef __attribute__((ext_vector_type(8))) short bfrag;   // 8 bf16 = 4 VGPR
typedef __attribute__((ext_vector_type(4))) float ffrag;   // 4 f32 (MFMA C/D)
typedef __attribute__((ext_vector_type(4))) float f32x4v;

// RNE float -> bf16 (bit math; matches numpy/JAX round-to-nearest-even)
__device__ __forceinline__ u16 f2bf(float f) {
  unsigned u = __float_as_uint(f);
  u += 0x7FFFu + ((u >> 16) & 1u);
  return (u16)(u >> 16);
}
__device__ __forceinline__ float bf2f(u16 u) {
  return __uint_as_float(((unsigned)u) << 16);
}

#define GLDS16(g, l)                                                  \
  __builtin_amdgcn_global_load_lds(                                   \
      (__attribute__((address_space(1))) const void*)(g),             \
      (__attribute__((address_space(3))) void*)(l), 16, 0, 0)

#define MEMFENCE() asm volatile("" ::: "memory")

// ---------------- split: f32 -> (bf16 hi, bf16 lo) ----------------
__global__ void __launch_bounds__(256) split_bf16_kernel(
    const float* __restrict__ in, u16* __restrict__ hi,
    u16* __restrict__ lo, long n4) {
  long i = (long)blockIdx.x * blockDim.x + threadIdx.x;
  const long stride = (long)gridDim.x * blockDim.x;
  for (; i < n4; i += stride) {
    f32x4v v = reinterpret_cast<const f32x4v*>(in)[i];
    u16 h[4], l[4];
#pragma unroll
    for (int j = 0; j < 4; ++j) {
      float f = v[j];
      u16 hb = f2bf(f);
      h[j] = hb;
      l[j] = f2bf(f - bf2f(hb));
    }
    ushort4 hv, lv;
    hv.x = h[0]; hv.y = h[1]; hv.z = h[2]; hv.w = h[3];
    lv.x = l[0]; lv.y = l[1]; lv.z = l[2]; lv.w = l[3];
    reinterpret_cast<ushort4*>(hi)[i] = hv;
    reinterpret_cast<ushort4*>(lo)[i] = lv;
  }
}

// ---------------- transpose f32 [R][C] -> bf16 [C][R] ----------------
__global__ void __launch_bounds__(256) transpose_bf16_kernel(
    const float* __restrict__ in, u16* __restrict__ out, int R, int C) {
  __shared__ u16 tile[64][65];
  const int bc = blockIdx.x << 6;
  const int br = blockIdx.y << 6;
  const int tc = threadIdx.x & 63;
  const int tr0 = threadIdx.x >> 6;
#pragma unroll
  for (int p = 0; p < 16; ++p) {
    int r = tr0 + (p << 2);
    tile[tc][r] = f2bf(in[(size_t)(br + r) * C + (bc + tc)]);
  }
  __syncthreads();
#pragma unroll
  for (int p = 0; p < 16; ++p) {
    int orow = tr0 + (p << 2);
    out[(size_t)(bc + orow) * R + (br + tc)] = tile[orow][tc];
  }
}

// ============ FUSED 3-term GEMM1:  yq = quant( xh*ph^T + xl*ph^T + xh*pl^T )
// BK=32, 128 K-tiles, units {Ah,Al,Bh,Bl} 16KB each, LDS 2buf x 64KB.
// 8 waves (2Mx4N), per-wave C=128x64. 5 phases/tile: hh(m0-3), hh(m4-7),
// lh(m0-3), lh(m4-7), hl(all m, Ah register-reused).
//
// COUNTED-WAIT schedule (T4): no lgkmcnt(0) asm -- ds_reads are compiler-
// visible loads, hipcc emits minimal counted lgkm waits per frag (m97).
// Unit-flight map (instr counts; each STAGE = 2 gload_lds):
//   steady state at P3-end: outstanding = Bl[t](2) + Ah,Al[t+1](4, P0) +
//     Bh,Bl[t+1](4, P1) = 10 -> vmcnt(8) drains Bl[t] for P4-top reads,
//     t+1 stages stay in flight under P4's 32-MFMA cluster.
//   tile-end: outstanding = 8 -> vmcnt(2): Ah,Al,Bh[t+1] landed (P0/P1/P2
//     reads of t+1), Bl[t+1] stays in flight 4 more phases.
//   tail t==127: no t+1/t+2 stages -> vmcnt(0) at P3-end covers Bl[127].
//   prologue: stage tile0 (8 instr), vmcnt(2) (Ah,Al,Bh landed; Bl waits
//     until P3-end's counted drain).
// WAR: every stage target's last ds_read completes within its consuming
// phase (compiler waits before MFMA use) >=2 barriers before the overwrite.
// Swizzle: byte ^= ((byte>>7)&7)<<4 both-sides; verified 0 conflicts (R5).
__global__ void __launch_bounds__(512, 2) gemm_fused3_kernel(
    const u16* __restrict__ Ah_, const u16* __restrict__ Al_,
    const u16* __restrict__ Bh_, const u16* __restrict__ Bl_,
    u16* __restrict__ Yq, const float* __restrict__ cent, int M, int N) {
  __shared__ __align__(16) char SM[131072];
  __shared__ float clut[16];
  const int tid = threadIdx.x;
  if (tid < 16) clut[tid] = cent[tid];

  // XCD swizzle (nwg=512, %8==0 -> bijective)
  const int nbn = N >> 8;
  const int nwg = (M >> 8) * nbn;
  int wg = blockIdx.x;
  wg = (wg & 7) * (nwg >> 3) + (wg >> 3);
  const int tm = (wg / nbn) << 8;
  const int tn = (wg % nbn) << 8;

  const int lane = tid & 63;
  const int wv = tid >> 6;
  const int wm = wv >> 2;  // 0..1
  const int wn = wv & 3;   // 0..3
  const int l15 = lane & 15;
  const int kslc = lane >> 4;

  // staging: dest linear, source pre-unswizzled (involution)
  const int Dst = tid * 16;
  const int Lg = Dst ^ (((Dst >> 7) & 7) << 4);
  const int srow = Lg >> 6;
  const int scol = (Lg & 63) >> 1;
  const size_t sOffA = (size_t)(tm + srow) * 4096 + scol;
  const size_t sOffB = (size_t)(tn + srow) * 4096 + scol;

  auto STAGE = [&](int u, const u16* base, int tau) {
    if (tau >= 128) return;
    const u16* src = base + (u < 2 ? sOffA : sOffB) + tau * 32;
    char* lds = SM + (tau & 1) * 65536 + u * 16384 + Dst;
    GLDS16(src, lds);
    GLDS16(src + (size_t)128 * 4096, lds + 8192);
  };

  const int slot16 = ((((l15 & 1) << 2) | kslc) ^ (l15 >> 1)) << 4;
  const int aOff = wm * 8192 + (l15 >> 1) * 128 + slot16;
  const int bOff = wn * 4096 + (l15 >> 1) * 128 + slot16;

#define LDSF(b, ubase, off, f)                                           \
  (*reinterpret_cast<const bfrag*>(SM + (b) * 65536 + (ubase) + (off) +  \
                                   (f) * 1024))

  ffrag acc[8][4];
#pragma unroll
  for (int m = 0; m < 8; ++m)
#pragma unroll
    for (int n = 0; n < 4; ++n) acc[m][n] = {0.f, 0.f, 0.f, 0.f};

  bfrag Ahf[8], Alf[4], Bhf[4], Blf[4];

  // prologue
  STAGE(0, Ah_, 0); STAGE(1, Al_, 0); STAGE(2, Bh_, 0); STAGE(3, Bl_, 0);
  asm volatile("s_waitcnt vmcnt(2)" ::: "memory");
  MEMFENCE();
  __builtin_amdgcn_s_barrier();

#define MFMA16(Aset, a0, Bset, mb)                                       \
  __builtin_amdgcn_s_setprio(1);                                         \
  _Pragma("unroll")                                                      \
  for (int m = 0; m < 4; ++m)                                            \
    _Pragma("unroll")                                                    \
    for (int n = 0; n < 4; ++n)                                          \
      acc[(mb) + m][n] = __builtin_amdgcn_mfma_f32_16x16x32_bf16(        \
          Aset[(a0) + m], Bset[n], acc[(mb) + m][n], 0, 0, 0);           \
  __builtin_amdgcn_s_setprio(0);

  for (int t = 0; t < 128; ++t) {
    const int b = t & 1;
    // ---- P0: read Ah[0-3], Bh; stage Ah,Al[t+1]; MFMA hh m0-3
#pragma unroll
    for (int f = 0; f < 4; ++f) Ahf[f] = LDSF(b, 0, aOff, f);
#pragma unroll
    for (int f = 0; f < 4; ++f) Bhf[f] = LDSF(b, 32768, bOff, f);
    STAGE(0, Ah_, t + 1); STAGE(1, Al_, t + 1);
    MEMFENCE();
    __builtin_amdgcn_s_barrier();
    MFMA16(Ahf, 0, Bhf, 0)
    MEMFENCE();
    __builtin_amdgcn_s_barrier();
    // ---- P1: read Ah[4-7]; stage Bh,Bl[t+1]; MFMA hh m4-7
#pragma unroll
    for (int f = 0; f < 4; ++f) Ahf[4 + f] = LDSF(b, 0, aOff, 4 + f);
    STAGE(2, Bh_, t + 1); STAGE(3, Bl_, t + 1);
    MEMFENCE();
    __builtin_amdgcn_s_barrier();
    MFMA16(Ahf, 4, Bhf, 4)
    MEMFENCE();
    __builtin_amdgcn_s_barrier();
    // ---- P2: read Al[0-3]; MFMA lh m0-3
#pragma unroll
    for (int f = 0; f < 4; ++f) Alf[f] = LDSF(b, 16384, aOff, f);
    MEMFENCE();
    __builtin_amdgcn_s_barrier();
    MFMA16(Alf, 0, Bhf, 0)
    MEMFENCE();
    __builtin_amdgcn_s_barrier();
    // ---- P3: read Al[4-7]; MFMA lh m4-7; counted drain of Bl[t]
#pragma unroll
    for (int f = 0; f < 4; ++f) Alf[f] = LDSF(b, 16384, aOff, 4 + f);
    MEMFENCE();
    __builtin_amdgcn_s_barrier();
    MFMA16(Alf, 0, Bhf, 4)
    if (t < 127)
      asm volatile("s_waitcnt vmcnt(8)" ::: "memory");  // Bl[t] landed
    else
      asm volatile("s_waitcnt vmcnt(0)" ::: "memory");  // tail: no t+1 cover
    MEMFENCE();
    __builtin_amdgcn_s_barrier();
    // ---- P4: read Bl; MFMA hl all m (32, Ah reg-reuse); counted tile-end
#pragma unroll
    for (int f = 0; f < 4; ++f) Blf[f] = LDSF(b, 49152, bOff, f);
    MEMFENCE();
    __builtin_amdgcn_s_barrier();
    MFMA16(Ahf, 0, Blf, 0)
    MFMA16(Ahf, 4, Blf, 4)
    // Ah,Al,Bh[t+1] landed for next tile's P0-P2; Bl[t+1] stays in flight
    asm volatile("s_waitcnt vmcnt(2)" ::: "memory");
    MEMFENCE();
    __builtin_amdgcn_s_barrier();
  }

  // quant epilogue; C/D mapping: col = lane&15, row = (lane>>4)*4 + reg
  const int r0 = tm + wm * 128 + kslc * 4;
  const int c0 = tn + wn * 64 + l15;
#pragma unroll
  for (int m = 0; m < 8; ++m)
#pragma unroll
    for (int n = 0; n < 4; ++n)
#pragma unroll
      for (int r = 0; r < 4; ++r) {
        float y = acc[m][n][r];
        float s = rintf((y + 1.0f) * 7.5f);  // RNE == jnp.round
        int idx = (int)s;
        idx = idx < 0 ? 0 : (idx > 15 ? 15 : idx);
        Yq[(size_t)(r0 + m * 16 + r) * N + (c0 + n * 16)] = f2bf(clut[idx]);
      }
#undef LDSF
#undef MFMA16
}

// ============ GEMM2 (R3 4-phase template, NSEG=1): out = yq @ Pi ==========
__global__ void __launch_bounds__(512, 2) gemm256_bt_kernel(
    const u16* __restrict__ A0, const u16* __restrict__ B0,
    float* __restrict__ Cout, int M, int N) {
  constexpr int NT = 64;
  __shared__ __align__(16) char SM[131072];
  const int tid = threadIdx.x;

  const int nbn = N >> 8;
  const int nwg = (M >> 8) * nbn;
  int wg = blockIdx.x;
  wg = (wg & 7) * (nwg >> 3) + (wg >> 3);
  const int tm = (wg / nbn) << 8;
  const int tn = (wg % nbn) << 8;

  const int lane = tid & 63;
  const int wv = tid >> 6;
  const int wm = wv >> 2;
  const int wn = wv & 3;
  const int l15 = lane & 15;
  const int kslc = lane >> 4;
  const int cXor = (lane & 7) << 4;

  const size_t thrOff =
      (size_t)(wv * 8 + (lane >> 3)) * 4096 + 8 * ((lane & 7) ^ (lane >> 3));
  const int ldsThr = wv * 1024 + lane * 16;

  auto STAGE = [&](int kind, int tau) {
    if (tau >= NT) return;
    const int b = tau & 1;
    const size_t ktE = (size_t)tau * 64;
    const u16* src;
    char* lds;
    if (kind >= 2) {
      const int idx = kind - 2;
      src = B0 + (size_t)(tn + idx * 128) * 4096 + ktE + thrOff;
      lds = SM + b * 65536 + 32768 + idx * 16384 + ldsThr;
    } else {
      src = A0 + (size_t)(tm + kind * 128) * 4096 + ktE + thrOff;
      lds = SM + b * 65536 + kind * 16384 + ldsThr;
    }
    GLDS16(src, lds);
    GLDS16(src + 262144, lds + 8192);
  };

#define LDSA(b, f, s)                                                      \
  (*reinterpret_cast<const bfrag*>(                                        \
      SM + (b) * 65536 + wm * 16384 + (((f) * 16 + l15) << 7) +            \
      ((((s) << 6) | (kslc << 4)) ^ cXor)))
#define LDSB(b, f, s)                                                      \
  (*reinterpret_cast<const bfrag*>(                                        \
      SM + (b) * 65536 + 32768 + (wn >> 1) * 16384 +                       \
      ((((wn & 1) * 64) + (f) * 16 + l15) << 7) +                          \
      ((((s) << 6) | (kslc << 4)) ^ cXor)))

  ffrag acc[8][4];
#pragma unroll
  for (int m = 0; m < 8; ++m)
#pragma unroll
    for (int n = 0; n < 4; ++n) acc[m][n] = {0.f, 0.f, 0.f, 0.f};

  STAGE(0, 0); STAGE(1, 0); STAGE(2, 0); STAGE(3, 0);
  STAGE(2, 1); STAGE(3, 1);
  asm volatile("s_waitcnt vmcnt(4)" ::: "memory");
  MEMFENCE();
  __builtin_amdgcn_s_barrier();

  bfrag Af[4], Bf[4];

  for (int t = 0; t < NT; ++t) {
    const int b = t & 1;
#pragma unroll
    for (int p = 0; p < 4; ++p) {
      const int s = p >> 1;
      const int mb = (p & 1) * 4;
      if ((p & 1) == 0) {
#pragma unroll
        for (int n = 0; n < 4; ++n) Bf[n] = LDSB(b, n, s);
      }
#pragma unroll
      for (int m = 0; m < 4; ++m) Af[m] = LDSA(b, mb + m, s);
      if (p == 0) STAGE(0, t + 1);
      else if (p == 1) STAGE(1, t + 1);
      else if (p == 3) { STAGE(2, t + 2); STAGE(3, t + 2); }
      MEMFENCE();
      __builtin_amdgcn_s_barrier();
      asm volatile("s_waitcnt lgkmcnt(0)" ::: "memory");
      __builtin_amdgcn_s_setprio(1);
#pragma unroll
      for (int m = 0; m < 4; ++m)
#pragma unroll
        for (int n = 0; n < 4; ++n)
          acc[mb + m][n] = __builtin_amdgcn_mfma_f32_16x16x32_bf16(
              Af[m], Bf[n], acc[mb + m][n], 0, 0, 0);
      __builtin_amdgcn_s_setprio(0);
      if (p == 3) {
        if (t == NT - 2)
          asm volatile("s_waitcnt vmcnt(0)" ::: "memory");
        else if (t < NT - 2)
          asm volatile("s_waitcnt vmcnt(4)" ::: "memory");
      }
      MEMFENCE();
      __builtin_amdgcn_s_barrier();
    }
  }

  const int r0 = tm + wm * 128 + kslc * 4;
  const int c0 = tn + wn * 64 + l15;
#pragma unroll
  for (int m = 0; m < 8; ++m)
#pragma unroll
    for (int n = 0; n < 4; ++n)
#pragma unroll
      for (int r = 0; r < 4; ++r)
        Cout[(size_t)(r0 + m * 16 + r) * N + (c0 + n * 16)] = acc[m][n][r];
#undef LDSA
#undef LDSB
}

extern "C" void kernel_launch(void* const* d_in, const int* in_sizes, int n_in,
                              void* d_out, int out_size, void* d_ws, size_t ws_size,
                              hipStream_t stream) {
  const float* x = (const float*)d_in[0];     // [8192][4096]
  const float* Pi = (const float*)d_in[1];    // [4096][4096]
  const float* cent = (const float*)d_in[2];  // [16]
  float* out = (float*)d_out;                 // [8192][4096]

  const size_t MB = (size_t)1 << 20;
  if (ws_size < 288 * MB) return;

  char* ws = (char*)d_ws;
  u16* x_hi = (u16*)(ws + 0 * MB);    // 64MB  bf16(x)
  u16* x_lo = (u16*)(ws + 64 * MB);   // 64MB  bf16(x - x_hi)
  u16* p_hi = (u16*)(ws + 128 * MB);  // 32MB  bf16(Pi)
  u16* p_lo = (u16*)(ws + 160 * MB);  // 32MB  bf16(Pi - p_hi)
  u16* piT  = (u16*)(ws + 192 * MB);  // 32MB  bf16(Pi^T)
  u16* yq   = (u16*)(ws + 224 * MB);  // 64MB  bf16(quantize(x @ Pi^T))

  split_bf16_kernel<<<2048, 256, 0, stream>>>(x, x_hi, x_lo, (long)NTOK * DD / 4);
  split_bf16_kernel<<<1024, 256, 0, stream>>>(Pi, p_hi, p_lo, (long)DD * DD / 4);
  transpose_bf16_kernel<<<dim3(DD / 64, DD / 64), 256, 0, stream>>>(Pi, piT, DD, DD);

  // GEMM1 fused 3-term + quantize -> yq
  gemm_fused3_kernel<<<512, 512, 0, stream>>>(
      x_hi, x_lo, p_hi, p_lo, yq, cent, NTOK, DD);
  // GEMM2: out = yq @ Pi
  gemm256_bt_kernel<<<512, 512, 0, stream>>>(yq, piT, out, NTOK, DD);
}